// Round 1
// baseline (485.369 us; speedup 1.0000x reference)
//
#include <hip/hip_runtime.h>
#include <hip/hip_bf16.h>

// Problem constants (from reference setup_inputs)
#define BC    8
#define NC    512
#define NRELC 4096

typedef unsigned short u16;
typedef __attribute__((ext_vector_type(4))) float  f32x4;
typedef __attribute__((ext_vector_type(8))) __bf16 bf16x8;
typedef __attribute__((ext_vector_type(8))) short  s16x8;

__device__ __forceinline__ u16 f2b(float f) {
  union { float f; unsigned u; } v; v.f = f;
  unsigned u = v.u;
  return (u16)((u + 0x7fffu + ((u >> 16) & 1u)) >> 16);  // RNE
}

// ---- recover gather indices from one-hot Rr/Rs -----------------------------
// Rr[b][n][r] == 1 iff recv[b,r]==n. Coalesced scan over r.
__global__ void extract_idx_kernel(const float* __restrict__ Rr,
                                   const float* __restrict__ Rs,
                                   int* __restrict__ recv, int* __restrict__ send) {
  int bn = blockIdx.x;              // b*NC + n
  int b = bn >> 9, n = bn & 511;
  const float* rr = Rr + (long)bn * NRELC;
  const float* rs = Rs + (long)bn * NRELC;
  for (int r = threadIdx.x; r < NRELC; r += blockDim.x) {
    if (rr[r] > 0.5f) recv[b * NRELC + r] = n;
    if (rs[r] > 0.5f) send[b * NRELC + r] = n;
  }
}

// ---- weight transpose + bf16: W[K][N] fp32 -> Wt[N][K] bf16 ----------------
__global__ void wtrans_kernel(const float* __restrict__ W, u16* __restrict__ Wt,
                              int K, int N) {
  int i = blockIdx.x * 256 + threadIdx.x;
  if (i >= K * N) return;
  int n = i / K, k = i - n * K;
  Wt[i] = f2b(W[k * N + n]);
}

// ---- build relation-encoder input [32768][160] bf16: [state_r|state_s|Ra] --
__global__ void build_rel_in_kernel(const float* __restrict__ state,
                                    const float* __restrict__ Ra,
                                    const int* __restrict__ recv,
                                    const int* __restrict__ send,
                                    u16* __restrict__ out) {
  long i = (long)blockIdx.x * 256 + threadIdx.x;
  int row = (int)(i / 160), c = (int)(i - (long)row * 160);
  int b = row >> 12;  // NREL=4096
  float v;
  if (c < 64)       v = state[((long)(b * NC + recv[row])) * 64 + c];
  else if (c < 128) v = state[((long)(b * NC + send[row])) * 64 + (c - 64)];
  else              v = Ra[(long)row * 32 + (c - 128)];
  out[i] = f2b(v);
}

// ---- scatter-add relations -> particles (fp32 atomics) ---------------------
__global__ void scatter_add_kernel(const float* __restrict__ releff,
                                   const int* __restrict__ recv,
                                   float* agg) {
  long i = (long)blockIdx.x * 256 + threadIdx.x;  // 32768*128 exact
  int row = (int)(i >> 7), c = (int)(i & 127);
  int b = row >> 12;
  atomicAdd(&agg[((long)(b * NC + recv[row])) * 128 + c], releff[i]);
}

// ---- MFMA GEMM: C[M][N] = act(A[M][K] @ W[K][N] + bias + addC) -------------
// Wt is pre-transposed bf16 [N][K]. 4 waves/block, each wave: 16 rows x N.
// A fp32 or bf16 (template), optional row gather (arow=(m>>12)*NC+gidx[m]).
// mfma_f32_16x16x32_bf16: A-frag lane: row=lane&15, k=(lane>>4)*8+j
//                         B-frag lane: k=(lane>>4)*8+j, col=lane&15
//                         C/D: row=(lane>>4)*4+reg, col=lane&15  [m89-verified]
template<int NT, bool AF32, bool OBF16, bool RELU, bool GATHER>
__global__ __launch_bounds__(256) void gemm_kernel(
    const void* __restrict__ Ap, const u16* __restrict__ Wt,
    const float* __restrict__ bias, const float* addC,
    void* Cp, const int* __restrict__ gidx, int M, int K) {
  constexpr int N = NT * 16;
  int wid = threadIdx.x >> 6, lane = threadIdx.x & 63;
  int m0 = blockIdx.x * 64 + wid * 16;
  int rl = lane & 15, kg = lane >> 4;
  int m = m0 + rl;
  long arow = m;
  if (GATHER) arow = (long)(m >> 12) * NC + gidx[m];

  f32x4 acc[NT];
#pragma unroll
  for (int t = 0; t < NT; ++t) acc[t] = (f32x4){0.f, 0.f, 0.f, 0.f};

  for (int k0 = 0; k0 < K; k0 += 32) {
    int kk = k0 + kg * 8;
    bf16x8 af;
    if (AF32) {
      const float* ap = (const float*)Ap + arow * K + kk;
      f32x4 lo = *(const f32x4*)ap;
      f32x4 hi = *(const f32x4*)(ap + 4);
      s16x8 s;
      s[0] = (short)f2b(lo[0]); s[1] = (short)f2b(lo[1]);
      s[2] = (short)f2b(lo[2]); s[3] = (short)f2b(lo[3]);
      s[4] = (short)f2b(hi[0]); s[5] = (short)f2b(hi[1]);
      s[6] = (short)f2b(hi[2]); s[7] = (short)f2b(hi[3]);
      af = __builtin_bit_cast(bf16x8, s);
    } else {
      af = *reinterpret_cast<const bf16x8*>((const u16*)Ap + arow * K + kk);
    }
    const u16* wb = Wt + kk;
#pragma unroll
    for (int t = 0; t < NT; ++t) {
      bf16x8 bf = *reinterpret_cast<const bf16x8*>(wb + (size_t)(t * 16 + rl) * K);
      acc[t] = __builtin_amdgcn_mfma_f32_16x16x32_bf16(af, bf, acc[t], 0, 0, 0);
    }
  }

  int orow = m0 + kg * 4;
#pragma unroll
  for (int t = 0; t < NT; ++t) {
    int gc = t * 16 + rl;
    float bv = bias ? bias[gc] : 0.f;
#pragma unroll
    for (int r = 0; r < 4; ++r) {
      int gr = orow + r;
      float v = acc[t][r] + bv;
      if (addC) v += addC[(long)gr * N + gc];
      if (RELU) v = fmaxf(v, 0.f);
      if (OBF16) ((u16*)Cp)[(long)gr * N + gc] = f2b(v);
      else       ((float*)Cp)[(long)gr * N + gc] = v;
    }
  }
}

extern "C" void kernel_launch(void* const* d_in, const int* in_sizes, int n_in,
                              void* d_out, int out_size, void* d_ws, size_t ws_size,
                              hipStream_t stream) {
  const float* state = (const float*)d_in[0];
  const float* Rr    = (const float*)d_in[1];
  const float* Rs    = (const float*)d_in[2];
  const float* Ra    = (const float*)d_in[3];
  const float* pe0_w = (const float*)d_in[4];  const float* pe0_b = (const float*)d_in[5];
  const float* pe1_w = (const float*)d_in[6];  const float* pe1_b = (const float*)d_in[7];
  const float* pe2_w = (const float*)d_in[8];  const float* pe2_b = (const float*)d_in[9];
  const float* re0_w = (const float*)d_in[10]; const float* re0_b = (const float*)d_in[11];
  const float* re1_w = (const float*)d_in[12]; const float* re1_b = (const float*)d_in[13];
  const float* re2_w = (const float*)d_in[14]; const float* re2_b = (const float*)d_in[15];
  const float* rp_w  = (const float*)d_in[16]; const float* rp_b  = (const float*)d_in[17];
  const float* pp_w  = (const float*)d_in[18]; const float* pp_b  = (const float*)d_in[19];
  const float* pr0_w = (const float*)d_in[20]; const float* pr0_b = (const float*)d_in[21];
  const float* pr1_w = (const float*)d_in[22]; const float* pr1_b = (const float*)d_in[23];
  // d_in[24] = pstep (always 3 per setup_inputs; hardcoded below)

  char* base = (char*)d_ws; size_t off = 0;
  auto alloc = [&](size_t b) -> void* {
    void* p = base + off; off = (off + b + 255) & ~(size_t)255; return p;
  };

  int* recv = (int*)alloc(4L * BC * NRELC);
  int* send = (int*)alloc(4L * BC * NRELC);
  u16* pe0t = (u16*)alloc(2L * 128 * 64);
  u16* pe1t = (u16*)alloc(2L * 128 * 128);
  u16* pe2t = (u16*)alloc(2L * 128 * 128);
  u16* re0t = (u16*)alloc(2L * 256 * 160);
  u16* re1t = (u16*)alloc(2L * 256 * 256);
  u16* re2t = (u16*)alloc(2L * 256 * 256);
  u16* rp0t = (u16*)alloc(2L * 128 * 256);
  u16* rp1t = (u16*)alloc(2L * 128 * 128);
  u16* rp2t = (u16*)alloc(2L * 128 * 128);
  u16* pp0t = (u16*)alloc(2L * 128 * 128);
  u16* pp1t = (u16*)alloc(2L * 128 * 128);
  u16* pr0t = (u16*)alloc(2L * 128 * 128);
  u16* pr1t = (u16*)alloc(2L * 64 * 128);
  u16* relin = (u16*)alloc(2L * 32768 * 160);
  u16* r1    = (u16*)alloc(2L * 32768 * 256);
  u16* r2    = (u16*)alloc(2L * 32768 * 256);
  float* rbase = (float*)alloc(4L * 32768 * 128);
  float* tmp   = (float*)alloc(4L * 32768 * 128);   // also holds relation_effect
  u16* x1   = (u16*)alloc(2L * 4096 * 128);
  u16* x2   = (u16*)alloc(2L * 4096 * 128);
  u16* penc = (u16*)alloc(2L * 4096 * 128);
  float* pbase = (float*)alloc(4L * 4096 * 128);
  float* agg   = (float*)alloc(4L * 4096 * 128);
  u16* peff = (u16*)alloc(2L * 4096 * 128);
  u16* h    = (u16*)alloc(2L * 4096 * 128);
  (void)ws_size; (void)in_sizes; (void)n_in; (void)out_size;

  extract_idx_kernel<<<BC * NC, 256, 0, stream>>>(Rr, Rs, recv, send);

  auto wt = [&](const float* W, u16* T, int K, int N) {
    wtrans_kernel<<<(K * N + 255) / 256, 256, 0, stream>>>(W, T, K, N);
  };
  wt(pe0_w, pe0t, 64, 128);
  wt(pe1_w, pe1t, 128, 128);
  wt(pe2_w, pe2t, 128, 128);
  wt(re0_w, re0t, 160, 256);
  wt(re1_w, re1t, 256, 256);
  wt(re2_w, re2t, 256, 256);
  wt(rp_w,             rp0t, 256, 128);   // K rows 0..255   (relation_encode)
  wt(rp_w + 256 * 128, rp1t, 128, 128);   // K rows 256..383 (effect_r)
  wt(rp_w + 384 * 128, rp2t, 128, 128);   // K rows 384..511 (effect_s)
  wt(pp_w,             pp0t, 128, 128);   // K rows 0..127   (particle_encode)
  wt(pp_w + 128 * 128, pp1t, 128, 128);   // K rows 128..255 (effect_agg)
  wt(pr0_w, pr0t, 128, 128);
  wt(pr1_w, pr1t, 128, 64);

  build_rel_in_kernel<<<(32768 * 160) / 256, 256, 0, stream>>>(state, Ra, recv, send, relin);

  // particle encoder MLP3 (M=4096)
  gemm_kernel<8, true,  true, true, false><<<64, 256, 0, stream>>>(state, pe0t, pe0_b, nullptr, x1, nullptr, 4096, 64);
  gemm_kernel<8, false, true, true, false><<<64, 256, 0, stream>>>(x1, pe1t, pe1_b, nullptr, x2, nullptr, 4096, 128);
  gemm_kernel<8, false, true, true, false><<<64, 256, 0, stream>>>(x2, pe2t, pe2_b, nullptr, penc, nullptr, 4096, 128);

  // relation encoder MLP3 (M=32768)
  gemm_kernel<16, false, true, true, false><<<512, 256, 0, stream>>>(relin, re0t, re0_b, nullptr, r1, nullptr, 32768, 160);
  gemm_kernel<16, false, true, true, false><<<512, 256, 0, stream>>>(r1, re1t, re1_b, nullptr, r2, nullptr, 32768, 256);
  gemm_kernel<16, false, true, true, false><<<512, 256, 0, stream>>>(r2, re2t, re2_b, nullptr, r1, nullptr, 32768, 256);

  // loop-invariant bases
  gemm_kernel<8, false, false, false, false><<<512, 256, 0, stream>>>(r1, rp0t, rp_b, nullptr, rbase, nullptr, 32768, 256);
  gemm_kernel<8, false, false, false, false><<<64, 256, 0, stream>>>(penc, pp0t, pp_b, nullptr, pbase, nullptr, 4096, 128);

  hipMemsetAsync(peff, 0, 2L * 4096 * 128, stream);  // particle_effect = 0

  for (int s = 0; s < 3; ++s) {  // pstep = 3
    // tmp = rel_base + gather_recv(peff) @ rp1t
    gemm_kernel<8, false, false, false, true><<<512, 256, 0, stream>>>(peff, rp1t, nullptr, rbase, tmp, recv, 32768, 128);
    // tmp = relu(tmp + gather_send(peff) @ rp2t)   (in-place: per-element read-then-write)
    gemm_kernel<8, false, false, true, true><<<512, 256, 0, stream>>>(peff, rp2t, nullptr, tmp, tmp, send, 32768, 128);
    hipMemsetAsync(agg, 0, 4L * 4096 * 128, stream);
    scatter_add_kernel<<<(32768 * 128) / 256, 256, 0, stream>>>(tmp, recv, agg);
    // peff = relu(part_base + agg @ pp1t)
    gemm_kernel<8, true, true, true, false><<<64, 256, 0, stream>>>(agg, pp1t, nullptr, pbase, peff, nullptr, 4096, 128);
  }

  // decoder
  gemm_kernel<8, false, true, true, false><<<64, 256, 0, stream>>>(peff, pr0t, pr0_b, nullptr, h, nullptr, 4096, 128);
  gemm_kernel<4, false, false, false, false><<<64, 256, 0, stream>>>(h, pr1t, pr1_b, nullptr, d_out, nullptr, 4096, 128);
}

// Round 2
// 347.000 us; speedup vs baseline: 1.3988x; 1.3988x over previous
//
#include <hip/hip_runtime.h>
#include <hip/hip_bf16.h>

#define BC    8
#define NC    512
#define NRELC 4096

typedef unsigned short u16;
typedef __attribute__((ext_vector_type(4))) float  f32x4;
typedef __attribute__((ext_vector_type(8))) __bf16 bf16x8;
typedef __attribute__((ext_vector_type(8))) short  s16x8;
typedef __attribute__((ext_vector_type(4))) u16    u16x4;

__device__ __forceinline__ u16 f2b(float f) {
  union { float f; unsigned u; } v; v.f = f;
  unsigned u = v.u;
  return (u16)((u + 0x7fffu + ((u >> 16) & 1u)) >> 16);  // RNE
}

// ---- recover gather indices from one-hot Rr/Rs (f32x4 vectorized) ----------
__global__ void extract_idx_v2(const float* __restrict__ Rr,
                               const float* __restrict__ Rs,
                               int* __restrict__ recv, int* __restrict__ send) {
  int bn = blockIdx.x;              // b*NC + n
  int b = bn >> 9, n = bn & 511;
  const f32x4* rr = (const f32x4*)(Rr + (long)bn * NRELC);
  const f32x4* rs = (const f32x4*)(Rs + (long)bn * NRELC);
#pragma unroll
  for (int it = 0; it < 4; ++it) {
    int r4 = threadIdx.x + it * 256;          // 1024 vec4 per row
    f32x4 a = rr[r4], s = rs[r4];
#pragma unroll
    for (int j = 0; j < 4; ++j) {
      if (a[j] > 0.5f) recv[b * NRELC + r4 * 4 + j] = n;
      if (s[j] > 0.5f) send[b * NRELC + r4 * 4 + j] = n;
    }
  }
}

// ---- all 13 weight transposes in one kernel --------------------------------
struct WT13 {
  const float* src[13];
  u16* dst[13];
  int K[13], N[13];
  int cum[14];   // cumulative element counts
};

__global__ void wtrans_all_kernel(WT13 wt) {
  int idx = blockIdx.x * 256 + threadIdx.x;
  if (idx >= wt.cum[13]) return;
  int w = 0;
  while (idx >= wt.cum[w + 1]) ++w;
  int i = idx - wt.cum[w];
  int K = wt.K[w], N = wt.N[w];
  int n = i / K, k = i - n * K;
  wt.dst[w][i] = f2b(wt.src[w][k * N + n]);
}

// ---- build relation-encoder input [32768][160] bf16 (vec4) -----------------
__global__ void build_rel_in_v2(const float* __restrict__ state,
                                const float* __restrict__ Ra,
                                const int* __restrict__ recv,
                                const int* __restrict__ send,
                                u16* __restrict__ out) {
  int i = blockIdx.x * 256 + threadIdx.x;      // over 32768*40 vec4 slots
  int row = i / 40, c4 = (i - row * 40) * 4;
  int b = row >> 12;
  f32x4 v;
  if (c4 < 64)       v = *(const f32x4*)&state[((long)(b * NC + recv[row])) * 64 + c4];
  else if (c4 < 128) v = *(const f32x4*)&state[((long)(b * NC + send[row])) * 64 + (c4 - 64)];
  else               v = *(const f32x4*)&Ra[(long)row * 32 + (c4 - 128)];
  u16x4 o;
  o[0] = f2b(v[0]); o[1] = f2b(v[1]); o[2] = f2b(v[2]); o[3] = f2b(v[3]);
  *(u16x4*)&out[(long)row * 160 + c4] = o;
}

// ---- step-0 scatter: agg += relu(rbase), rows scattered by recv ------------
__global__ void rscatter0_kernel(const float* __restrict__ rbase,
                                 const int* __restrict__ recv,
                                 float* agg) {
  int i = blockIdx.x * 256 + threadIdx.x;      // over 32768*32 vec4 slots
  int row = i >> 5, c4 = (i & 31) * 4;
  int b = row >> 12;
  f32x4 v = *(const f32x4*)&rbase[(long)row * 128 + c4];
  float* dst = &agg[((long)(b * NC + recv[row])) * 128 + c4];
#pragma unroll
  for (int j = 0; j < 4; ++j) atomicAdd(dst + j, fmaxf(v[j], 0.f));
}

// ---- GEMM v2: C[M][NLD] = act(A @ Wt^T + bias + addC) ----------------------
// Waves tiled WM x WN over the block tile; each wave: MT row-tiles x NT col-tiles.
// B-fragment loaded once per (k0,t) and reused across MT MFMAs.
// mfma_f32_16x16x32_bf16 layouts per m89/m91 (A: row=lane&15,k=kg*8+j; C/D:
// col=lane&15, row=kg*4+reg).
template<int WM, int WN, int MT, int NT, bool AF32, bool OBF16, bool RELU>
__global__ __launch_bounds__(WM* WN * 64) void gemm2_kernel(
    const void* __restrict__ Ap, const u16* __restrict__ Wt,
    const float* __restrict__ bias, const float* __restrict__ addC,
    void* Cp, int K, int NLD) {
  int wid = threadIdx.x >> 6, lane = threadIdx.x & 63;
  int wm = wid / WN, wn = wid - wm * WN;
  int rl = lane & 15, kg = lane >> 4;
  int m0 = blockIdx.x * (WM * MT * 16) + wm * (MT * 16);
  int n0 = blockIdx.y * (WN * NT * 16) + wn * (NT * 16);

  f32x4 acc[MT][NT];
#pragma unroll
  for (int mt = 0; mt < MT; ++mt)
#pragma unroll
    for (int t = 0; t < NT; ++t) acc[mt][t] = (f32x4){0.f, 0.f, 0.f, 0.f};

  for (int k0 = 0; k0 < K; k0 += 32) {
    int kk = k0 + kg * 8;
    bf16x8 af[MT];
#pragma unroll
    for (int mt = 0; mt < MT; ++mt) {
      long row = m0 + mt * 16 + rl;
      if (AF32) {
        const float* ap = (const float*)Ap + row * K + kk;
        f32x4 lo = *(const f32x4*)ap;
        f32x4 hi = *(const f32x4*)(ap + 4);
        s16x8 s;
        s[0] = (short)f2b(lo[0]); s[1] = (short)f2b(lo[1]);
        s[2] = (short)f2b(lo[2]); s[3] = (short)f2b(lo[3]);
        s[4] = (short)f2b(hi[0]); s[5] = (short)f2b(hi[1]);
        s[6] = (short)f2b(hi[2]); s[7] = (short)f2b(hi[3]);
        af[mt] = __builtin_bit_cast(bf16x8, s);
      } else {
        af[mt] = *reinterpret_cast<const bf16x8*>((const u16*)Ap + row * K + kk);
      }
    }
#pragma unroll
    for (int t = 0; t < NT; ++t) {
      bf16x8 bf = *reinterpret_cast<const bf16x8*>(Wt + (size_t)(n0 + t * 16 + rl) * K + kk);
#pragma unroll
      for (int mt = 0; mt < MT; ++mt)
        acc[mt][t] = __builtin_amdgcn_mfma_f32_16x16x32_bf16(af[mt], bf, acc[mt][t], 0, 0, 0);
    }
  }

#pragma unroll
  for (int mt = 0; mt < MT; ++mt) {
    int orow = m0 + mt * 16 + kg * 4;
#pragma unroll
    for (int t = 0; t < NT; ++t) {
      int gc = n0 + t * 16 + rl;
      float bv = bias ? bias[gc] : 0.f;
#pragma unroll
      for (int r = 0; r < 4; ++r) {
        long gr = orow + r;
        float v = acc[mt][t][r] + bv;
        if (addC) v += addC[gr * NLD + gc];
        if (RELU) v = fmaxf(v, 0.f);
        if (OBF16) ((u16*)Cp)[gr * NLD + gc] = f2b(v);
        else       ((float*)Cp)[gr * NLD + gc] = v;
      }
    }
  }
}

// ---- fused relation step: agg += relu(rbase + Er@rp1 + Es@rp2) scattered ---
// Er/Es = peff rows gathered by recv/send. K=128, N=128.
template<int WM, int WN, int MT, int NT>
__global__ __launch_bounds__(WM* WN * 64) void relstep_kernel(
    const u16* __restrict__ peff, const u16* __restrict__ rp1t,
    const u16* __restrict__ rp2t, const float* __restrict__ rbase,
    const int* __restrict__ recv, const int* __restrict__ send,
    float* agg) {
  constexpr int K = 128;
  int wid = threadIdx.x >> 6, lane = threadIdx.x & 63;
  int wm = wid / WN, wn = wid - wm * WN;
  int rl = lane & 15, kg = lane >> 4;
  int m0 = blockIdx.x * (WM * MT * 16) + wm * (MT * 16);
  int n0 = wn * (NT * 16);

  long grow[MT], srow[MT];
#pragma unroll
  for (int mt = 0; mt < MT; ++mt) {
    int gr = m0 + mt * 16 + rl;
    int b = gr >> 12;
    grow[mt] = (long)(b * NC + recv[gr]) * K;
    srow[mt] = (long)(b * NC + send[gr]) * K;
  }

  f32x4 acc[MT][NT];
#pragma unroll
  for (int mt = 0; mt < MT; ++mt)
#pragma unroll
    for (int t = 0; t < NT; ++t) acc[mt][t] = (f32x4){0.f, 0.f, 0.f, 0.f};

  for (int k0 = 0; k0 < K; k0 += 32) {
    int kk = k0 + kg * 8;
    bf16x8 af[MT];
#pragma unroll
    for (int mt = 0; mt < MT; ++mt)
      af[mt] = *reinterpret_cast<const bf16x8*>(peff + grow[mt] + kk);
#pragma unroll
    for (int t = 0; t < NT; ++t) {
      bf16x8 bf = *reinterpret_cast<const bf16x8*>(rp1t + (size_t)(n0 + t * 16 + rl) * K + kk);
#pragma unroll
      for (int mt = 0; mt < MT; ++mt)
        acc[mt][t] = __builtin_amdgcn_mfma_f32_16x16x32_bf16(af[mt], bf, acc[mt][t], 0, 0, 0);
    }
#pragma unroll
    for (int mt = 0; mt < MT; ++mt)
      af[mt] = *reinterpret_cast<const bf16x8*>(peff + srow[mt] + kk);
#pragma unroll
    for (int t = 0; t < NT; ++t) {
      bf16x8 bf = *reinterpret_cast<const bf16x8*>(rp2t + (size_t)(n0 + t * 16 + rl) * K + kk);
#pragma unroll
      for (int mt = 0; mt < MT; ++mt)
        acc[mt][t] = __builtin_amdgcn_mfma_f32_16x16x32_bf16(af[mt], bf, acc[mt][t], 0, 0, 0);
    }
  }

#pragma unroll
  for (int mt = 0; mt < MT; ++mt) {
    int orow = m0 + mt * 16 + kg * 4;
#pragma unroll
    for (int r = 0; r < 4; ++r) {
      int gr = orow + r;
      int b = gr >> 12;
      float* dst = &agg[(long)(b * NC + recv[gr]) * 128];
      const float* rb = &rbase[(long)gr * 128];
#pragma unroll
      for (int t = 0; t < NT; ++t) {
        int gc = n0 + t * 16 + rl;
        float v = fmaxf(acc[mt][t][r] + rb[gc], 0.f);
        atomicAdd(dst + gc, v);
      }
    }
  }
}

extern "C" void kernel_launch(void* const* d_in, const int* in_sizes, int n_in,
                              void* d_out, int out_size, void* d_ws, size_t ws_size,
                              hipStream_t stream) {
  const float* state = (const float*)d_in[0];
  const float* Rr    = (const float*)d_in[1];
  const float* Rs    = (const float*)d_in[2];
  const float* Ra    = (const float*)d_in[3];
  const float* pe0_w = (const float*)d_in[4];  const float* pe0_b = (const float*)d_in[5];
  const float* pe1_w = (const float*)d_in[6];  const float* pe1_b = (const float*)d_in[7];
  const float* pe2_w = (const float*)d_in[8];  const float* pe2_b = (const float*)d_in[9];
  const float* re0_w = (const float*)d_in[10]; const float* re0_b = (const float*)d_in[11];
  const float* re1_w = (const float*)d_in[12]; const float* re1_b = (const float*)d_in[13];
  const float* re2_w = (const float*)d_in[14]; const float* re2_b = (const float*)d_in[15];
  const float* rp_w  = (const float*)d_in[16]; const float* rp_b  = (const float*)d_in[17];
  const float* pp_w  = (const float*)d_in[18]; const float* pp_b  = (const float*)d_in[19];
  const float* pr0_w = (const float*)d_in[20]; const float* pr0_b = (const float*)d_in[21];
  const float* pr1_w = (const float*)d_in[22]; const float* pr1_b = (const float*)d_in[23];
  // d_in[24] = pstep == 3 (fixed by setup_inputs)

  char* base = (char*)d_ws; size_t off = 0;
  auto alloc = [&](size_t b) -> void* {
    void* p = base + off; off = (off + b + 255) & ~(size_t)255; return p;
  };

  int* recv = (int*)alloc(4L * BC * NRELC);
  int* send = (int*)alloc(4L * BC * NRELC);
  u16* pe0t = (u16*)alloc(2L * 128 * 64);
  u16* pe1t = (u16*)alloc(2L * 128 * 128);
  u16* pe2t = (u16*)alloc(2L * 128 * 128);
  u16* re0t = (u16*)alloc(2L * 256 * 160);
  u16* re1t = (u16*)alloc(2L * 256 * 256);
  u16* re2t = (u16*)alloc(2L * 256 * 256);
  u16* rp0t = (u16*)alloc(2L * 128 * 256);
  u16* rp1t = (u16*)alloc(2L * 128 * 128);
  u16* rp2t = (u16*)alloc(2L * 128 * 128);
  u16* pp0t = (u16*)alloc(2L * 128 * 128);
  u16* pp1t = (u16*)alloc(2L * 128 * 128);
  u16* pr0t = (u16*)alloc(2L * 128 * 128);
  u16* pr1t = (u16*)alloc(2L * 64 * 128);
  u16* relin = (u16*)alloc(2L * 32768 * 160);
  u16* r1    = (u16*)alloc(2L * 32768 * 256);
  u16* r2    = (u16*)alloc(2L * 32768 * 256);
  float* rbase = (float*)alloc(4L * 32768 * 128);
  u16* x1   = (u16*)alloc(2L * 4096 * 128);
  u16* x2   = (u16*)alloc(2L * 4096 * 128);
  u16* penc = (u16*)alloc(2L * 4096 * 128);
  float* pbase = (float*)alloc(4L * 4096 * 128);
  float* agg   = (float*)alloc(4L * 4096 * 128);
  u16* peff = (u16*)alloc(2L * 4096 * 128);
  u16* h    = (u16*)alloc(2L * 4096 * 128);
  (void)ws_size; (void)in_sizes; (void)n_in; (void)out_size;

  // 1. indices
  extract_idx_v2<<<BC * NC, 256, 0, stream>>>(Rr, Rs, recv, send);

  // 2. all weight transposes in one kernel
  WT13 wt;
  const float* srcs[13] = {pe0_w, pe1_w, pe2_w, re0_w, re1_w, re2_w,
                           rp_w, rp_w + 256 * 128, rp_w + 384 * 128,
                           pp_w, pp_w + 128 * 128, pr0_w, pr1_w};
  u16* dsts[13] = {pe0t, pe1t, pe2t, re0t, re1t, re2t,
                   rp0t, rp1t, rp2t, pp0t, pp1t, pr0t, pr1t};
  int Ks[13] = {64, 128, 128, 160, 256, 256, 256, 128, 128, 128, 128, 128, 128};
  int Ns[13] = {128, 128, 128, 256, 256, 256, 128, 128, 128, 128, 128, 128, 64};
  int cum = 0;
  for (int i = 0; i < 13; ++i) {
    wt.src[i] = srcs[i]; wt.dst[i] = dsts[i]; wt.K[i] = Ks[i]; wt.N[i] = Ns[i];
    wt.cum[i] = cum; cum += Ks[i] * Ns[i];
  }
  wt.cum[13] = cum;
  wtrans_all_kernel<<<(cum + 255) / 256, 256, 0, stream>>>(wt);

  // 3. relation-encoder input
  build_rel_in_v2<<<(32768 * 40) / 256, 256, 0, stream>>>(state, Ra, recv, send, relin);

  // 4. particle encoder MLP (M=4096): WM=4,WN=1,MT=1,NT=8 -> 64 blocks
  gemm2_kernel<4, 1, 1, 8, true,  true, true><<<dim3(64, 1), 256, 0, stream>>>(state, pe0t, pe0_b, nullptr, x1, 64, 128);
  gemm2_kernel<4, 1, 1, 8, false, true, true><<<dim3(64, 1), 256, 0, stream>>>(x1, pe1t, pe1_b, nullptr, x2, 128, 128);
  gemm2_kernel<4, 1, 1, 8, false, true, true><<<dim3(64, 1), 256, 0, stream>>>(x2, pe2t, pe2_b, nullptr, penc, 128, 128);

  // 5. relation encoder MLP (M=32768, N=256): WM=2,WN=2,MT=4,NT=8 -> 128x256/block, 256 blocks
  gemm2_kernel<2, 2, 4, 8, false, true, true><<<dim3(256, 1), 256, 0, stream>>>(relin, re0t, re0_b, nullptr, r1, 160, 256);
  gemm2_kernel<2, 2, 4, 8, false, true, true><<<dim3(256, 1), 256, 0, stream>>>(r1, re1t, re1_b, nullptr, r2, 256, 256);
  gemm2_kernel<2, 2, 4, 8, false, true, true><<<dim3(256, 1), 256, 0, stream>>>(r2, re2t, re2_b, nullptr, r1, 256, 256);

  // 6. loop-invariant bases
  //    rbase (M=32768, N=128): WM=2,WN=2,MT=4,NT=4 -> 128x128/block, 256 blocks
  gemm2_kernel<2, 2, 4, 4, false, false, false><<<dim3(256, 1), 256, 0, stream>>>(r1, rp0t, rp_b, nullptr, rbase, 256, 128);
  gemm2_kernel<4, 1, 1, 8, false, false, false><<<dim3(64, 1), 256, 0, stream>>>(penc, pp0t, pp_b, nullptr, pbase, 128, 128);

  // 7. propagation: step 0 (peff == 0 -> scatter relu(rbase) directly)
  hipMemsetAsync(agg, 0, 4L * 4096 * 128, stream);
  rscatter0_kernel<<<(32768 * 32) / 256, 256, 0, stream>>>(rbase, recv, agg);
  gemm2_kernel<4, 1, 1, 8, true, true, true><<<dim3(64, 1), 256, 0, stream>>>(agg, pp1t, nullptr, pbase, peff, 128, 128);

  //    steps 1,2: fused gather-GEMM-scatter
  for (int s = 1; s < 3; ++s) {
    hipMemsetAsync(agg, 0, 4L * 4096 * 128, stream);
    relstep_kernel<2, 2, 4, 4><<<dim3(256, 1), 256, 0, stream>>>(peff, rp1t, rp2t, rbase, recv, send, agg);
    gemm2_kernel<4, 1, 1, 8, true, true, true><<<dim3(64, 1), 256, 0, stream>>>(agg, pp1t, nullptr, pbase, peff, 128, 128);
  }

  // 8. decoder
  gemm2_kernel<4, 1, 1, 8, false, true, true><<<dim3(64, 1), 256, 0, stream>>>(peff, pr0t, pr0_b, nullptr, h, 128, 128);
  gemm2_kernel<4, 1, 1, 4, false, false, false><<<dim3(64, 1), 256, 0, stream>>>(h, pr1t, pr1_b, nullptr, d_out, 128, 64);
}

// Round 4
// 292.647 us; speedup vs baseline: 1.6585x; 1.1857x over previous
//
#include <hip/hip_runtime.h>
#include <hip/hip_bf16.h>

#define BC    8
#define NC    512
#define NRELC 4096
#define MAXDEG 64

typedef unsigned short u16;
typedef __attribute__((ext_vector_type(2))) float  f32x2;
typedef __attribute__((ext_vector_type(4))) float  f32x4;
typedef __attribute__((ext_vector_type(8))) __bf16 bf16x8;
typedef __attribute__((ext_vector_type(8))) short  s16x8;
typedef __attribute__((ext_vector_type(4))) u16    u16x4;

__device__ __forceinline__ u16 f2b(float f) {
  union { float f; unsigned u; } v; v.f = f;
  unsigned u = v.u;
  return (u16)((u + 0x7fffu + ((u >> 16) & 1u)) >> 16);  // RNE
}

// ---- extract indices + padded-CSR receiver lists ---------------------------
// Block bn=(b,n) scans Rr[b][n][:] / Rs[b][n][:]. Per-thread 16 consecutive r
// so thread order == r order -> deterministic ranks via block scan.
__global__ __launch_bounds__(256) void extract_csr(
    const float* __restrict__ Rr, const float* __restrict__ Rs,
    int* __restrict__ recv, int* __restrict__ send,
    int* __restrict__ deg, int* __restrict__ lists) {
  int bn = blockIdx.x;              // b*NC + n
  int b = bn >> 9, n = bn & 511;
  const float* rr = Rr + (long)bn * NRELC;
  const float* rs = Rs + (long)bn * NRELC;

  // Rs: coalesced vec4 scan, write send only
#pragma unroll
  for (int it = 0; it < 4; ++it) {
    int r4 = threadIdx.x + it * 256;
    f32x4 s = ((const f32x4*)rs)[r4];
#pragma unroll
    for (int j = 0; j < 4; ++j)
      if (s[j] > 0.5f) send[b * NRELC + r4 * 4 + j] = n;
  }

  // Rr: per-thread 16 consecutive r
  int rb = threadIdx.x * 16;
  f32x4 a[4];
#pragma unroll
  for (int q = 0; q < 4; ++q) a[q] = *(const f32x4*)(rr + rb + q * 4);
  int cnt = 0;
#pragma unroll
  for (int q = 0; q < 4; ++q)
#pragma unroll
    for (int j = 0; j < 4; ++j) cnt += (a[q][j] > 0.5f) ? 1 : 0;

  __shared__ int sc[256];
  sc[threadIdx.x] = cnt;
  __syncthreads();
  for (int ofs = 1; ofs < 256; ofs <<= 1) {
    int v = sc[threadIdx.x];
    int u = (threadIdx.x >= ofs) ? sc[threadIdx.x - ofs] : 0;
    __syncthreads();
    sc[threadIdx.x] = v + u;
    __syncthreads();
  }
  int pos = sc[threadIdx.x] - cnt;  // exclusive prefix
#pragma unroll
  for (int q = 0; q < 4; ++q)
#pragma unroll
    for (int j = 0; j < 4; ++j) {
      int r = rb + q * 4 + j;
      if (a[q][j] > 0.5f) {
        recv[b * NRELC + r] = n;
        lists[bn * MAXDEG + pos] = r;
        ++pos;
      }
    }
  if (threadIdx.x == 255) deg[bn] = sc[255];
}

// ---- all 13 weight transposes in one kernel --------------------------------
struct WT13 {
  const float* src[13];
  u16* dst[13];
  int K[13], N[13];
  int cum[14];
};

__global__ void wtrans_all_kernel(WT13 wt) {
  int idx = blockIdx.x * 256 + threadIdx.x;
  if (idx >= wt.cum[13]) return;
  int w = 0;
  while (idx >= wt.cum[w + 1]) ++w;
  int i = idx - wt.cum[w];
  int K = wt.K[w], N = wt.N[w];
  int n = i / K, k = i - n * K;
  wt.dst[w][i] = f2b(wt.src[w][k * N + n]);
}

// ---- build relation-encoder input [32768][160] bf16 (vec4) -----------------
__global__ void build_rel_in_v2(const float* __restrict__ state,
                                const float* __restrict__ Ra,
                                const int* __restrict__ recv,
                                const int* __restrict__ send,
                                u16* __restrict__ out) {
  int i = blockIdx.x * 256 + threadIdx.x;      // over 32768*40 vec4 slots
  int row = i / 40, c4 = (i - row * 40) * 4;
  int b = row >> 12;
  f32x4 v;
  if (c4 < 64)       v = *(const f32x4*)&state[((long)(b * NC + recv[row])) * 64 + c4];
  else if (c4 < 128) v = *(const f32x4*)&state[((long)(b * NC + send[row])) * 64 + (c4 - 64)];
  else               v = *(const f32x4*)&Ra[(long)row * 32 + (c4 - 128)];
  u16x4 o;
  o[0] = f2b(v[0]); o[1] = f2b(v[1]); o[2] = f2b(v[2]); o[3] = f2b(v[3]);
  *(u16x4*)&out[(long)row * 160 + c4] = o;
}

// ---- segmented gather-reduce: agg[p] = sum over incoming relation rows -----
// One wave per particle; lane covers 2 cols. src fp32 [32768][128].
template<bool RELU>
__global__ __launch_bounds__(256) void segreduce_kernel(
    const float* __restrict__ src, const int* __restrict__ deg,
    const int* __restrict__ lists, float* __restrict__ agg) {
  int wid = threadIdx.x >> 6, lane = threadIdx.x & 63;
  int p = blockIdx.x * 4 + wid;   // 1024 blocks x 4 waves = 4096 particles
  int b = p >> 9;
  int c = lane * 2;
  int d = deg[p];
  const int* lp = &lists[p * MAXDEG];
  f32x2 acc = (f32x2){0.f, 0.f};
  for (int k = 0; k < d; ++k) {
    long row = ((long)b * NRELC + lp[k]) * 128;
    f32x2 v = *(const f32x2*)&src[row + c];
    if (RELU) { v[0] = fmaxf(v[0], 0.f); v[1] = fmaxf(v[1], 0.f); }
    acc[0] += v[0]; acc[1] += v[1];
  }
  *(f32x2*)&agg[(long)p * 128 + c] = acc;
}

// ---- GEMM v2: C[M][NLD] = act(A @ Wt^T + bias + addC) ----------------------
template<int WM, int WN, int MT, int NT, bool AF32, bool OBF16, bool RELU>
__global__ __launch_bounds__(WM* WN * 64) void gemm2_kernel(
    const void* __restrict__ Ap, const u16* __restrict__ Wt,
    const float* __restrict__ bias, const float* __restrict__ addC,
    void* Cp, int K, int NLD) {
  int wid = threadIdx.x >> 6, lane = threadIdx.x & 63;
  int wm = wid / WN, wn = wid - wm * WN;
  int rl = lane & 15, kg = lane >> 4;
  int m0 = blockIdx.x * (WM * MT * 16) + wm * (MT * 16);
  int n0 = blockIdx.y * (WN * NT * 16) + wn * (NT * 16);

  f32x4 acc[MT][NT];
#pragma unroll
  for (int mt = 0; mt < MT; ++mt)
#pragma unroll
    for (int t = 0; t < NT; ++t) acc[mt][t] = (f32x4){0.f, 0.f, 0.f, 0.f};

  for (int k0 = 0; k0 < K; k0 += 32) {
    int kk = k0 + kg * 8;
    bf16x8 af[MT];
#pragma unroll
    for (int mt = 0; mt < MT; ++mt) {
      long row = m0 + mt * 16 + rl;
      if (AF32) {
        const float* ap = (const float*)Ap + row * K + kk;
        f32x4 lo = *(const f32x4*)ap;
        f32x4 hi = *(const f32x4*)(ap + 4);
        s16x8 s;
        s[0] = (short)f2b(lo[0]); s[1] = (short)f2b(lo[1]);
        s[2] = (short)f2b(lo[2]); s[3] = (short)f2b(lo[3]);
        s[4] = (short)f2b(hi[0]); s[5] = (short)f2b(hi[1]);
        s[6] = (short)f2b(hi[2]); s[7] = (short)f2b(hi[3]);
        af[mt] = __builtin_bit_cast(bf16x8, s);
      } else {
        af[mt] = *reinterpret_cast<const bf16x8*>((const u16*)Ap + row * K + kk);
      }
    }
#pragma unroll
    for (int t = 0; t < NT; ++t) {
      bf16x8 bf = *reinterpret_cast<const bf16x8*>(Wt + (size_t)(n0 + t * 16 + rl) * K + kk);
#pragma unroll
      for (int mt = 0; mt < MT; ++mt)
        acc[mt][t] = __builtin_amdgcn_mfma_f32_16x16x32_bf16(af[mt], bf, acc[mt][t], 0, 0, 0);
    }
  }

#pragma unroll
  for (int mt = 0; mt < MT; ++mt) {
    int orow = m0 + mt * 16 + kg * 4;
#pragma unroll
    for (int t = 0; t < NT; ++t) {
      int gc = n0 + t * 16 + rl;
      float bv = bias ? bias[gc] : 0.f;
#pragma unroll
      for (int r = 0; r < 4; ++r) {
        long gr = orow + r;
        float v = acc[mt][t][r] + bv;
        if (addC) v += addC[gr * NLD + gc];
        if (RELU) v = fmaxf(v, 0.f);
        if (OBF16) ((u16*)Cp)[gr * NLD + gc] = f2b(v);
        else       ((float*)Cp)[gr * NLD + gc] = v;
      }
    }
  }
}

// ---- fused relation step: tmp = relu(rbase + Er@rp1 + Es@rp2) --------------
// Er/Es = peff rows gathered by recv/send. K=128, N=128. Plain stores (no atomics).
template<int WM, int WN, int MT, int NT>
__global__ __launch_bounds__(WM* WN * 64) void relstep_kernel(
    const u16* __restrict__ peff, const u16* __restrict__ rp1t,
    const u16* __restrict__ rp2t, const float* __restrict__ rbase,
    const int* __restrict__ recv, const int* __restrict__ send,
    float* __restrict__ tmp) {
  constexpr int K = 128;
  int wid = threadIdx.x >> 6, lane = threadIdx.x & 63;
  int wm = wid / WN, wn = wid - wm * WN;
  int rl = lane & 15, kg = lane >> 4;
  int m0 = blockIdx.x * (WM * MT * 16) + wm * (MT * 16);
  int n0 = wn * (NT * 16);

  long grow[MT], srow[MT];
#pragma unroll
  for (int mt = 0; mt < MT; ++mt) {
    int gr = m0 + mt * 16 + rl;
    int b = gr >> 12;
    grow[mt] = (long)(b * NC + recv[gr]) * K;
    srow[mt] = (long)(b * NC + send[gr]) * K;
  }

  f32x4 acc[MT][NT];
#pragma unroll
  for (int mt = 0; mt < MT; ++mt)
#pragma unroll
    for (int t = 0; t < NT; ++t) acc[mt][t] = (f32x4){0.f, 0.f, 0.f, 0.f};

  for (int k0 = 0; k0 < K; k0 += 32) {
    int kk = k0 + kg * 8;
    bf16x8 af[MT];
#pragma unroll
    for (int mt = 0; mt < MT; ++mt)
      af[mt] = *reinterpret_cast<const bf16x8*>(peff + grow[mt] + kk);
#pragma unroll
    for (int t = 0; t < NT; ++t) {
      bf16x8 bf = *reinterpret_cast<const bf16x8*>(rp1t + (size_t)(n0 + t * 16 + rl) * K + kk);
#pragma unroll
      for (int mt = 0; mt < MT; ++mt)
        acc[mt][t] = __builtin_amdgcn_mfma_f32_16x16x32_bf16(af[mt], bf, acc[mt][t], 0, 0, 0);
    }
#pragma unroll
    for (int mt = 0; mt < MT; ++mt)
      af[mt] = *reinterpret_cast<const bf16x8*>(peff + srow[mt] + kk);
#pragma unroll
    for (int t = 0; t < NT; ++t) {
      bf16x8 bf = *reinterpret_cast<const bf16x8*>(rp2t + (size_t)(n0 + t * 16 + rl) * K + kk);
#pragma unroll
      for (int mt = 0; mt < MT; ++mt)
        acc[mt][t] = __builtin_amdgcn_mfma_f32_16x16x32_bf16(af[mt], bf, acc[mt][t], 0, 0, 0);
    }
  }

#pragma unroll
  for (int mt = 0; mt < MT; ++mt) {
    int orow = m0 + mt * 16 + kg * 4;
#pragma unroll
    for (int r = 0; r < 4; ++r) {
      long gr = orow + r;
      const float* rb = &rbase[gr * 128];
      float* dst = &tmp[gr * 128];
#pragma unroll
      for (int t = 0; t < NT; ++t) {
        int gc = n0 + t * 16 + rl;
        dst[gc] = fmaxf(acc[mt][t][r] + rb[gc], 0.f);
      }
    }
  }
}

extern "C" void kernel_launch(void* const* d_in, const int* in_sizes, int n_in,
                              void* d_out, int out_size, void* d_ws, size_t ws_size,
                              hipStream_t stream) {
  const float* state = (const float*)d_in[0];
  const float* Rr    = (const float*)d_in[1];
  const float* Rs    = (const float*)d_in[2];
  const float* Ra    = (const float*)d_in[3];
  const float* pe0_w = (const float*)d_in[4];  const float* pe0_b = (const float*)d_in[5];
  const float* pe1_w = (const float*)d_in[6];  const float* pe1_b = (const float*)d_in[7];
  const float* pe2_w = (const float*)d_in[8];  const float* pe2_b = (const float*)d_in[9];
  const float* re0_w = (const float*)d_in[10]; const float* re0_b = (const float*)d_in[11];
  const float* re1_w = (const float*)d_in[12]; const float* re1_b = (const float*)d_in[13];
  const float* re2_w = (const float*)d_in[14]; const float* re2_b = (const float*)d_in[15];
  const float* rp_w  = (const float*)d_in[16]; const float* rp_b  = (const float*)d_in[17];
  const float* pp_w  = (const float*)d_in[18]; const float* pp_b  = (const float*)d_in[19];
  const float* pr0_w = (const float*)d_in[20]; const float* pr0_b = (const float*)d_in[21];
  const float* pr1_w = (const float*)d_in[22]; const float* pr1_b = (const float*)d_in[23];
  // d_in[24] = pstep == 3 (fixed by setup_inputs)

  char* base = (char*)d_ws; size_t off = 0;
  auto alloc = [&](size_t b) -> void* {
    void* p = base + off; off = (off + b + 255) & ~(size_t)255; return p;
  };

  int* recv = (int*)alloc(4L * BC * NRELC);
  int* send = (int*)alloc(4L * BC * NRELC);
  int* deg   = (int*)alloc(4L * BC * NC);
  int* lists = (int*)alloc(4L * BC * NC * MAXDEG);
  u16* pe0t = (u16*)alloc(2L * 128 * 64);
  u16* pe1t = (u16*)alloc(2L * 128 * 128);
  u16* pe2t = (u16*)alloc(2L * 128 * 128);
  u16* re0t = (u16*)alloc(2L * 256 * 160);
  u16* re1t = (u16*)alloc(2L * 256 * 256);
  u16* re2t = (u16*)alloc(2L * 256 * 256);
  u16* rp0t = (u16*)alloc(2L * 128 * 256);
  u16* rp1t = (u16*)alloc(2L * 128 * 128);
  u16* rp2t = (u16*)alloc(2L * 128 * 128);
  u16* pp0t = (u16*)alloc(2L * 128 * 128);
  u16* pp1t = (u16*)alloc(2L * 128 * 128);
  u16* pr0t = (u16*)alloc(2L * 128 * 128);
  u16* pr1t = (u16*)alloc(2L * 64 * 128);
  u16* relin = (u16*)alloc(2L * 32768 * 160);
  u16* r1    = (u16*)alloc(2L * 32768 * 256);
  u16* r2    = (u16*)alloc(2L * 32768 * 256);
  float* rbase = (float*)alloc(4L * 32768 * 128);
  float* tmp   = (float*)alloc(4L * 32768 * 128);
  u16* x1   = (u16*)alloc(2L * 4096 * 128);
  u16* x2   = (u16*)alloc(2L * 4096 * 128);
  u16* penc = (u16*)alloc(2L * 4096 * 128);
  float* pbase = (float*)alloc(4L * 4096 * 128);
  float* agg   = (float*)alloc(4L * 4096 * 128);
  u16* peff = (u16*)alloc(2L * 4096 * 128);
  u16* h    = (u16*)alloc(2L * 4096 * 128);
  (void)ws_size; (void)in_sizes; (void)n_in; (void)out_size;

  // 1. indices + padded CSR
  extract_csr<<<BC * NC, 256, 0, stream>>>(Rr, Rs, recv, send, deg, lists);

  // 2. all weight transposes in one kernel.
  // One struct per line {src, dst, K, N} — fields can't misalign (R3 bug:
  // a dropped literal in parallel arrays scrambled pr0/pr1 strides).
  struct WSpec { const float* src; u16* dst; int K, N; };
  const WSpec specs[13] = {
      {pe0_w,            pe0t, 64, 128},
      {pe1_w,            pe1t, 128, 128},
      {pe2_w,            pe2t, 128, 128},
      {re0_w,            re0t, 160, 256},
      {re1_w,            re1t, 256, 256},
      {re2_w,            re2t, 256, 256},
      {rp_w,             rp0t, 256, 128},
      {rp_w + 256 * 128, rp1t, 128, 128},
      {rp_w + 384 * 128, rp2t, 128, 128},
      {pp_w,             pp0t, 128, 128},
      {pp_w + 128 * 128, pp1t, 128, 128},
      {pr0_w,            pr0t, 128, 128},
      {pr1_w,            pr1t, 128, 64},
  };
  WT13 wt;
  int cum = 0;
  for (int i = 0; i < 13; ++i) {
    wt.src[i] = specs[i].src; wt.dst[i] = specs[i].dst;
    wt.K[i] = specs[i].K; wt.N[i] = specs[i].N;
    wt.cum[i] = cum; cum += specs[i].K * specs[i].N;
  }
  wt.cum[13] = cum;
  wtrans_all_kernel<<<(cum + 255) / 256, 256, 0, stream>>>(wt);

  // 3. relation-encoder input
  build_rel_in_v2<<<(32768 * 40) / 256, 256, 0, stream>>>(state, Ra, recv, send, relin);

  // 4. particle encoder MLP (M=4096)
  gemm2_kernel<4, 1, 1, 8, true,  true, true><<<dim3(64, 1), 256, 0, stream>>>(state, pe0t, pe0_b, nullptr, x1, 64, 128);
  gemm2_kernel<4, 1, 1, 8, false, true, true><<<dim3(64, 1), 256, 0, stream>>>(x1, pe1t, pe1_b, nullptr, x2, 128, 128);
  gemm2_kernel<4, 1, 1, 8, false, true, true><<<dim3(64, 1), 256, 0, stream>>>(x2, pe2t, pe2_b, nullptr, penc, 128, 128);

  // 5. relation encoder MLP (M=32768, N=256)
  gemm2_kernel<2, 2, 4, 8, false, true, true><<<dim3(256, 1), 256, 0, stream>>>(relin, re0t, re0_b, nullptr, r1, 160, 256);
  gemm2_kernel<2, 2, 4, 8, false, true, true><<<dim3(256, 1), 256, 0, stream>>>(r1, re1t, re1_b, nullptr, r2, 256, 256);
  gemm2_kernel<2, 2, 4, 8, false, true, true><<<dim3(256, 1), 256, 0, stream>>>(r2, re2t, re2_b, nullptr, r1, 256, 256);

  // 6. loop-invariant bases
  gemm2_kernel<2, 2, 4, 4, false, false, false><<<dim3(256, 1), 256, 0, stream>>>(r1, rp0t, rp_b, nullptr, rbase, 256, 128);
  gemm2_kernel<4, 1, 1, 8, false, false, false><<<dim3(64, 1), 256, 0, stream>>>(penc, pp0t, pp_b, nullptr, pbase, 128, 128);

  // 7. propagation
  //    step 0: peff==0 -> agg = segreduce(relu(rbase))
  segreduce_kernel<true><<<1024, 256, 0, stream>>>(rbase, deg, lists, agg);
  gemm2_kernel<4, 1, 1, 8, true, true, true><<<dim3(64, 1), 256, 0, stream>>>(agg, pp1t, nullptr, pbase, peff, 128, 128);

  //    steps 1,2: gather-GEMM -> tmp, then segreduce
  for (int s = 1; s < 3; ++s) {
    relstep_kernel<2, 2, 4, 4><<<dim3(256, 1), 256, 0, stream>>>(peff, rp1t, rp2t, rbase, recv, send, tmp);
    segreduce_kernel<false><<<1024, 256, 0, stream>>>(tmp, deg, lists, agg);
    gemm2_kernel<4, 1, 1, 8, true, true, true><<<dim3(64, 1), 256, 0, stream>>>(agg, pp1t, nullptr, pbase, peff, 128, 128);
  }

  // 8. decoder
  gemm2_kernel<4, 1, 1, 8, false, true, true><<<dim3(64, 1), 256, 0, stream>>>(peff, pr0t, pr0_b, nullptr, h, 128, 128);
  gemm2_kernel<4, 1, 1, 4, false, false, false><<<dim3(64, 1), 256, 0, stream>>>(h, pr1t, pr1_b, nullptr, d_out, 128, 64);
}